// Round 6
// baseline (133.272 us; speedup 1.0000x reference)
//
#include <hip/hip_runtime.h>

// RandomForest: 131072 samples x 64 feat, 64 trees depth 12, 8-class vote.
//
// R15: R9/R14 walk partition, but the per-tree PAIRS tables (levels 0..9,
// 341x16B = 5.5KB/tree) are staged into LDS per 4-tree window, removing
// their scattered L2 requests. Per-(wave,tree) scattered 64B lines: pairs
// ~63 (coverage 63/86 = 73% -> staging wins), sub ~57 (coverage 57/256 =
// 22% -> staging loses, stays in L2). Model: L2 lines 15.7M -> ~10.6M ->
// walk 48 -> ~33us. Chain check vs R13's failure: 16 waves/CU x ILP-4 =
// 16 chains/SIMD (R13 died at 2), and pair steps are now ~120cyc LDS not
// ~300cyc L2. LDS = 64KB X tile + 86KB pairs window = 150KB -> 1 block/CU.
// Sub (levels 10,11 + leaves) unchanged from global; votes/vbuf as R9.

constexpr int kSamples  = 131072;
constexpr int kFeat     = 64;
constexpr int kTrees    = 64;
constexpr int kInternal = 4095;
constexpr int kClasses  = 8;

constexpr int TPB  = 1024;
constexpr int SPB  = 256;                        // samples per block
constexpr int XSTR = 256;                        // dwords; f column = f<<10 bytes
constexpr int XLDS_BYTES = kFeat * XSTR * 4;     // 65536 B
constexpr int TREES_PER_THREAD = 16;             // 4 thread-slices per sample
constexpr int WTREES = 4;                        // trees per window (ILP)
constexpr int NWIN   = TREES_PER_THREAD / WTREES;// 4 windows
constexpr int PTREE  = 344;                      // padded pairs entries per tree
constexpr int PAIR_LDS_BYTES = 4 * WTREES * PTREE * 16;   // 88064
constexpr int TOTAL_LDS = XLDS_BYTES + PAIR_LDS_BYTES;    // 153600 (<=160K)

// Pair p covers levels 2p,2p+1; entries-before offsets {0,1,5,21,85}, 341/tree,
// stride 512 -> tree base = t<<9.
struct Pair  { float thr0, thrL, thrR; unsigned meta; };  // meta: f0|fL<<6|fR<<12
struct Sub16 { float thr10, thrL, thrR; unsigned meta; }; // +lv0..lv3 <<18,21,24,27

constexpr int kPairItems = kTrees * 341;              // 21824
constexpr int kSubItems  = kTrees * 1024;             // 65536
constexpr int kPackItems = kPairItems + kSubItems;    // 87360

// ---------------- fused pack kernel (one launch) ----------------

__global__ __launch_bounds__(256) void pack_kernel(
    const int* __restrict__ features, const float* __restrict__ thresholds,
    const int* __restrict__ leaf_values,
    Pair* __restrict__ pairsA, Sub16* __restrict__ subsA)
{
    int g = blockIdx.x * 256 + threadIdx.x;
    if (g < kPairItems) {
        int t = g / 341;
        int e = g - t * 341;
        int p, m;
        if      (e < 1)  { p = 0; m = e; }
        else if (e < 5)  { p = 1; m = e - 1; }
        else if (e < 21) { p = 2; m = e - 5; }
        else if (e < 85) { p = 3; m = e - 21; }
        else             { p = 4; m = e - 85; }
        int g0 = (1 << (2 * p)) - 1 + m;              // global node id at level 2p
        int b  = t * kInternal;
        Pair pr;
        pr.thr0 = thresholds[b + g0];
        pr.thrL = thresholds[b + 2 * g0 + 1];
        pr.thrR = thresholds[b + 2 * g0 + 2];
        pr.meta = (unsigned)features[b + g0]
                | ((unsigned)features[b + 2 * g0 + 1] << 6)
                | ((unsigned)features[b + 2 * g0 + 2] << 12);
        pairsA[(t << 9) + e] = pr;
    } else if (g < kPackItems) {
        int i2 = g - kPairItems;
        int t = i2 >> 10;
        int j = i2 & 1023;                             // level-10 local index
        int n10 = 1023 + j;
        int b   = t * kInternal;
        Sub16 sb;
        sb.thr10 = thresholds[b + n10];
        sb.thrL  = thresholds[b + 2 * n10 + 1];
        sb.thrR  = thresholds[b + 2 * n10 + 2];
        const int* lv = leaf_values + ((t << 12) + 4 * j);
        sb.meta = (unsigned)features[b + n10]
                | ((unsigned)features[b + 2 * n10 + 1] << 6)
                | ((unsigned)features[b + 2 * n10 + 2] << 12)
                | ((unsigned)lv[0] << 18) | ((unsigned)lv[1] << 21)
                | ((unsigned)lv[2] << 24) | ((unsigned)lv[3] << 27);
        subsA[(t << 10) + j] = sb;
    }
}

// ---------------- walk kernel ----------------

__global__ __launch_bounds__(TPB, 1) void forest_kernel(
    const float* __restrict__ X,
    const Pair*  __restrict__ pairsA,   // [64][512] (341 used)
    const Sub16* __restrict__ subsA,    // [64][1024]
    int* __restrict__ out)
{
    extern __shared__ char lds[];
    float* xs = (float*)lds;                       // [64][256] feature-major
    Pair*  pl = (Pair*)(lds + XLDS_BYTES);         // [4 quarters][4 trees][344]

    const int tid  = threadIdx.x;
    const int s    = tid & (SPB - 1);              // sample slot 0..255
    const int h    = tid >> 8;                     // forest quarter 0..3
    const int base = blockIdx.x * SPB;

    Pair* plh = pl + h * (WTREES * PTREE);         // this quarter's window slab

    // Stage X: 4 threads per sample each load a quarter-row (4 float4).
    // LDS writes at f*256+s -> bank = s%32, consecutive lanes = 2-way (free).
    {
        const float4* Xr = (const float4*)(X + (size_t)(base + s) * kFeat) + h * 4;
        #pragma unroll
        for (int k = 0; k < 4; ++k) {
            float4 v = Xr[k];
            int f0 = (h * 4 + k) * 4;
            xs[(f0 + 0) * XSTR + s] = v.x;
            xs[(f0 + 1) * XSTR + s] = v.y;
            xs[(f0 + 2) * XSTR + s] = v.z;
            xs[(f0 + 3) * XSTR + s] = v.w;
        }
    }

    // Stage window 0 pairs: quarter's 256 threads load 4 trees x 344 entries.
    // Entries 341..343 are in-allocation pad (stride 512), never read back.
    {
        const Pair* src = pairsA + ((h * TREES_PER_THREAD) << 9);
        #pragma unroll
        for (int tr = 0; tr < WTREES; ++tr) {
            plh[tr * PTREE + s] = src[(tr << 9) + s];
            int e2 = s + 256;
            if (e2 < PTREE) plh[tr * PTREE + e2] = src[(tr << 9) + e2];
        }
    }
    __syncthreads();

    const char* xb = (const char*)xs + (s << 2);   // + (f<<10) per access
    unsigned long long votes = 0ull;

    const int mofs[4] = {0, 1, 5, 21};             // shallow pair offsets

    for (int w = 0; w < NWIN; ++w) {
        const int t0 = h * TREES_PER_THREAD + w * WTREES;

        int m[WTREES];
        #pragma unroll
        for (int j = 0; j < WTREES; ++j) m[j] = 0;

        #pragma unroll
        for (int p = 0; p < 4; ++p) {              // levels 0..7, pairs from LDS
            #pragma unroll
            for (int j = 0; j < WTREES; ++j) {     // 4 independent chains
                Pair pr = plh[j * PTREE + mofs[p] + m[j]];
                float x0 = *(const float*)(xb + ((pr.meta & 63u) << 10));
                int c0 = x0 > pr.thr0 ? 1 : 0;
                float thr1     = c0 ? pr.thrR : pr.thrL;
                unsigned fsel  = c0 ? (pr.meta >> 12) : (pr.meta >> 6);
                float x1 = *(const float*)(xb + ((fsel & 63u) << 10));
                int c1 = x1 > thr1 ? 1 : 0;
                m[j] = 4 * m[j] + 2 * c0 + c1;
            }
        }

        #pragma unroll
        for (int j = 0; j < WTREES; ++j) {         // levels 8,9 from LDS
            Pair pr = plh[j * PTREE + 85 + m[j]];
            float x0 = *(const float*)(xb + ((pr.meta & 63u) << 10));
            int c0 = x0 > pr.thr0 ? 1 : 0;
            float thr1     = c0 ? pr.thrR : pr.thrL;
            unsigned fsel  = c0 ? (pr.meta >> 12) : (pr.meta >> 6);
            float x1 = *(const float*)(xb + ((fsel & 63u) << 10));
            int c1 = x1 > thr1 ? 1 : 0;
            m[j] = 4 * m[j] + 2 * c0 + c1;
        }

        #pragma unroll
        for (int j = 0; j < WTREES; ++j) {         // levels 10,11 + leaf (L2)
            Sub16 sb = subsA[((t0 + j) << 10) + m[j]];
            unsigned mt = sb.meta;
            float x0 = *(const float*)(xb + ((mt & 63u) << 10));
            int c0 = x0 > sb.thr10 ? 1 : 0;
            float thr1    = c0 ? sb.thrR : sb.thrL;
            unsigned fsel = c0 ? (mt >> 12) : (mt >> 6);
            float x1 = *(const float*)(xb + ((fsel & 63u) << 10));
            int c1 = x1 > thr1 ? 1 : 0;
            int cls = (mt >> (18 + 3 * ((c0 << 1) | c1))) & 7;
            votes += 1ull << (cls << 3);
        }

        if (w + 1 < NWIN) {
            __syncthreads();                       // all reads of window w done
            const Pair* src = pairsA +
                ((h * TREES_PER_THREAD + (w + 1) * WTREES) << 9);
            #pragma unroll
            for (int tr = 0; tr < WTREES; ++tr) {
                plh[tr * PTREE + s] = src[(tr << 9) + s];
                int e2 = s + 256;
                if (e2 < PTREE) plh[tr * PTREE + e2] = src[(tr << 9) + e2];
            }
            __syncthreads();                       // window w+1 staged
        }
    }

    // Combine 4 partial vote vectors per sample through LDS (xs dead now).
    __syncthreads();
    unsigned long long* vbuf = (unsigned long long*)xs;   // 3*256 u64 = 6 KiB
    if (h != 0) vbuf[(h - 1) * SPB + s] = votes;
    __syncthreads();
    if (h == 0) {
        votes += vbuf[s] + vbuf[SPB + s] + vbuf[2 * SPB + s];
        // argmax over 8 packed byte counters; strict '>' keeps smallest class
        int best = 0;
        int bc   = (int)(votes & 0xFFull);
        #pragma unroll
        for (int c = 1; c < kClasses; ++c) {
            int cnt = (int)((votes >> (c * 8)) & 0xFFull);
            if (cnt > bc) { bc = cnt; best = c; }
        }
        out[base + s] = best;
    }
}

extern "C" void kernel_launch(void* const* d_in, const int* in_sizes, int n_in,
                              void* d_out, int out_size, void* d_ws, size_t ws_size,
                              hipStream_t stream) {
    const float* X          = (const float*)d_in[0];
    const int*   features   = (const int*)d_in[1];
    const float* thresholds = (const float*)d_in[2];
    const int*   leaves     = (const int*)d_in[3];
    int*         out        = (int*)d_out;

    Pair*  pairsA = (Pair*)d_ws;                            // 64*512*16 = 512 KiB
    Sub16* subsA  = (Sub16*)((char*)d_ws + (kTrees << 13)); // +512 KiB, 1 MiB

    (void)hipFuncSetAttribute((const void*)forest_kernel,
                              hipFuncAttributeMaxDynamicSharedMemorySize,
                              TOTAL_LDS);

    pack_kernel<<<(kPackItems + 255) / 256, 256, 0, stream>>>(
        features, thresholds, leaves, pairsA, subsA);
    forest_kernel<<<kSamples / SPB, TPB, TOTAL_LDS, stream>>>(
        X, pairsA, subsA, out);
}

// Round 8
// 116.408 us; speedup vs baseline: 1.1449x; 1.1449x over previous
//
#include <hip/hip_runtime.h>

// RandomForest: 131072 samples x 64 feat, 64 trees depth 12, 8-class vote.
//
// R17 = R14/R16 resubmitted verbatim (R16 hit a container-infra flake; this
// exact source already passed in R5: total 116.8us, walk 47.8us). Best
// verified kernel.
//
// Structural limit argument (twice-verified): walk issues ~15.7M
// birthday-distinct 64B L2 line-requests (per wave-tree: p0..p3 ~23,
// p85 ~40.7, sub ~57); model 51us vs measured 47.8us (7%). VALU busy-time
// floor ~22us, fully overlapped. Alternatives all measured net-negative:
// cooperative fusion +260us & uncapturable (R10/R11); one-tree-at-a-time
// L1 residency +60us, chain-ILP starvation (R13); LDS table staging +16us,
// 11.7M bank-conflict cycles from random ds_read_b128 (R15). Remaining
// ~60us of dur_us above the walk is harness-fixed (constant across 2- and
// 3-launch variants).
//
// Walk structure (measured 47.8us steady, twice): 256 samples/block in a
// 64KB feature-major LDS tile, TPB=1024, 4 threads/sample (16 trees each =
// 2 ILP-8 windows), grid=512 -> 2 blocks/CU -> 32 waves/CU (8/SIMD).

constexpr int kSamples  = 131072;
constexpr int kFeat     = 64;
constexpr int kTrees    = 64;
constexpr int kInternal = 4095;
constexpr int kClasses  = 8;

constexpr int TPB  = 1024;
constexpr int SPB  = 256;                        // samples per block
constexpr int XSTR = 256;                        // dwords; f column = f<<10 bytes
constexpr int XLDS_BYTES = kFeat * XSTR * 4;     // 65536 B
constexpr int ILP  = 8;
constexpr int TREES_PER_THREAD = 16;             // 4 thread-slices per sample

// Pair p covers levels 2p,2p+1; entries-before offsets {0,1,5,21,85}, 341/tree,
// stride 512 -> tree base = t<<9.
struct Pair  { float thr0, thrL, thrR; unsigned meta; };  // meta: f0|fL<<6|fR<<12
struct Sub16 { float thr10, thrL, thrR; unsigned meta; }; // +lv0..lv3 <<18,21,24,27

constexpr int kPairItems = kTrees * 341;              // 21824
constexpr int kSubItems  = kTrees * 1024;             // 65536
constexpr int kPackItems = kPairItems + kSubItems;    // 87360

// ---------------- fused pack kernel (one launch) ----------------

__global__ __launch_bounds__(256) void pack_kernel(
    const int* __restrict__ features, const float* __restrict__ thresholds,
    const int* __restrict__ leaf_values,
    Pair* __restrict__ pairsA, Sub16* __restrict__ subsA)
{
    int g = blockIdx.x * 256 + threadIdx.x;
    if (g < kPairItems) {
        int t = g / 341;
        int e = g - t * 341;
        int p, m;
        if      (e < 1)  { p = 0; m = e; }
        else if (e < 5)  { p = 1; m = e - 1; }
        else if (e < 21) { p = 2; m = e - 5; }
        else if (e < 85) { p = 3; m = e - 21; }
        else             { p = 4; m = e - 85; }
        int g0 = (1 << (2 * p)) - 1 + m;              // global node id at level 2p
        int b  = t * kInternal;
        Pair pr;
        pr.thr0 = thresholds[b + g0];
        pr.thrL = thresholds[b + 2 * g0 + 1];
        pr.thrR = thresholds[b + 2 * g0 + 2];
        pr.meta = (unsigned)features[b + g0]
                | ((unsigned)features[b + 2 * g0 + 1] << 6)
                | ((unsigned)features[b + 2 * g0 + 2] << 12);
        pairsA[(t << 9) + e] = pr;
    } else if (g < kPackItems) {
        int i2 = g - kPairItems;
        int t = i2 >> 10;
        int j = i2 & 1023;                             // level-10 local index
        int n10 = 1023 + j;
        int b   = t * kInternal;
        Sub16 sb;
        sb.thr10 = thresholds[b + n10];
        sb.thrL  = thresholds[b + 2 * n10 + 1];
        sb.thrR  = thresholds[b + 2 * n10 + 2];
        const int* lv = leaf_values + ((t << 12) + 4 * j);
        sb.meta = (unsigned)features[b + n10]
                | ((unsigned)features[b + 2 * n10 + 1] << 6)
                | ((unsigned)features[b + 2 * n10 + 2] << 12)
                | ((unsigned)lv[0] << 18) | ((unsigned)lv[1] << 21)
                | ((unsigned)lv[2] << 24) | ((unsigned)lv[3] << 27);
        subsA[(t << 10) + j] = sb;
    }
}

// ---------------- walk kernel (R9 verbatim) ----------------

__global__ __launch_bounds__(TPB, 8) void forest_kernel(
    const float* __restrict__ X,
    const Pair*  __restrict__ pairsA,   // [64][512] (341 used)
    const Sub16* __restrict__ subsA,    // [64][1024]
    int* __restrict__ out)
{
    extern __shared__ float xs[];                  // [64][256] feature-major
    const int tid  = threadIdx.x;
    const int s    = tid & (SPB - 1);              // sample slot 0..255
    const int h    = tid >> 8;                     // forest quarter 0..3
    const int base = blockIdx.x * SPB;

    // Stage: 4 threads per sample each load a quarter-row (4 float4).
    // LDS writes at f*256+s -> bank = s%32, consecutive lanes = 2-way (free).
    {
        const float4* Xr = (const float4*)(X + (size_t)(base + s) * kFeat) + h * 4;
        #pragma unroll
        for (int k = 0; k < 4; ++k) {
            float4 v = Xr[k];
            int f0 = (h * 4 + k) * 4;
            xs[(f0 + 0) * XSTR + s] = v.x;
            xs[(f0 + 1) * XSTR + s] = v.y;
            xs[(f0 + 2) * XSTR + s] = v.z;
            xs[(f0 + 3) * XSTR + s] = v.w;
        }
    }
    __syncthreads();

    const char* xb = (const char*)xs + (s << 2);   // + (f<<10) per access
    unsigned long long votes = 0ull;

    const int mofs[4] = {0, 1, 5, 21};             // shallow pair offsets

    const int tbeg = h * TREES_PER_THREAD;
    for (int t0 = tbeg; t0 < tbeg + TREES_PER_THREAD; t0 += ILP) {
        int m[ILP];
        #pragma unroll
        for (int j = 0; j < ILP; ++j) m[j] = 0;

        #pragma unroll
        for (int p = 0; p < 4; ++p) {              // levels 0..7
            #pragma unroll
            for (int j = 0; j < ILP; ++j) {        // 8 independent chains
                Pair pr = pairsA[((t0 + j) << 9) + mofs[p] + m[j]];
                float x0 = *(const float*)(xb + ((pr.meta & 63u) << 10));
                int c0 = x0 > pr.thr0 ? 1 : 0;
                float thr1     = c0 ? pr.thrR : pr.thrL;
                unsigned fsel  = c0 ? (pr.meta >> 12) : (pr.meta >> 6);
                float x1 = *(const float*)(xb + ((fsel & 63u) << 10));
                int c1 = x1 > thr1 ? 1 : 0;
                m[j] = 4 * m[j] + 2 * c0 + c1;
            }
        }

        #pragma unroll
        for (int j = 0; j < ILP; ++j) {            // levels 8,9 (pair4)
            Pair pr = pairsA[((t0 + j) << 9) + 85 + m[j]];
            float x0 = *(const float*)(xb + ((pr.meta & 63u) << 10));
            int c0 = x0 > pr.thr0 ? 1 : 0;
            float thr1     = c0 ? pr.thrR : pr.thrL;
            unsigned fsel  = c0 ? (pr.meta >> 12) : (pr.meta >> 6);
            float x1 = *(const float*)(xb + ((fsel & 63u) << 10));
            int c1 = x1 > thr1 ? 1 : 0;
            m[j] = 4 * m[j] + 2 * c0 + c1;
        }

        #pragma unroll
        for (int j = 0; j < ILP; ++j) {            // levels 10,11 + leaf
            Sub16 sb = subsA[((t0 + j) << 10) + m[j]];
            unsigned mt = sb.meta;
            float x0 = *(const float*)(xb + ((mt & 63u) << 10));
            int c0 = x0 > sb.thr10 ? 1 : 0;
            float thr1    = c0 ? sb.thrR : sb.thrL;
            unsigned fsel = c0 ? (mt >> 12) : (mt >> 6);
            float x1 = *(const float*)(xb + ((fsel & 63u) << 10));
            int c1 = x1 > thr1 ? 1 : 0;
            int cls = (mt >> (18 + 3 * ((c0 << 1) | c1))) & 7;
            votes += 1ull << (cls << 3);
        }
    }

    // Combine 4 partial vote vectors per sample through LDS (xs dead now).
    __syncthreads();
    unsigned long long* vbuf = (unsigned long long*)xs;   // 3*256 u64 = 6 KiB
    if (h != 0) vbuf[(h - 1) * SPB + s] = votes;
    __syncthreads();
    if (h == 0) {
        votes += vbuf[s] + vbuf[SPB + s] + vbuf[2 * SPB + s];
        // argmax over 8 packed byte counters; strict '>' keeps smallest class
        int best = 0;
        int bc   = (int)(votes & 0xFFull);
        #pragma unroll
        for (int c = 1; c < kClasses; ++c) {
            int cnt = (int)((votes >> (c * 8)) & 0xFFull);
            if (cnt > bc) { bc = cnt; best = c; }
        }
        out[base + s] = best;
    }
}

extern "C" void kernel_launch(void* const* d_in, const int* in_sizes, int n_in,
                              void* d_out, int out_size, void* d_ws, size_t ws_size,
                              hipStream_t stream) {
    const float* X          = (const float*)d_in[0];
    const int*   features   = (const int*)d_in[1];
    const float* thresholds = (const float*)d_in[2];
    const int*   leaves     = (const int*)d_in[3];
    int*         out        = (int*)d_out;

    Pair*  pairsA = (Pair*)d_ws;                            // 64*512*16 = 512 KiB
    Sub16* subsA  = (Sub16*)((char*)d_ws + (kTrees << 13)); // +512 KiB, 1 MiB

    (void)hipFuncSetAttribute((const void*)forest_kernel,
                              hipFuncAttributeMaxDynamicSharedMemorySize,
                              XLDS_BYTES);

    pack_kernel<<<(kPackItems + 255) / 256, 256, 0, stream>>>(
        features, thresholds, leaves, pairsA, subsA);
    forest_kernel<<<kSamples / SPB, TPB, XLDS_BYTES, stream>>>(
        X, pairsA, subsA, out);
}